// Round 14
// baseline (365.483 us; speedup 1.0000x reference)
//
#include <hip/hip_runtime.h>
#include <hip/hip_bf16.h>

typedef __bf16 bf16_t;
typedef unsigned char u8;
typedef float  f32x4  __attribute__((ext_vector_type(4)));
typedef int    i32x4  __attribute__((ext_vector_type(4)));
typedef int    i32x8  __attribute__((ext_vector_type(8)));
typedef __attribute__((address_space(3))) unsigned as3u32;
typedef __attribute__((address_space(1))) unsigned as1u32;

#define Bdim 4
#define Sdim 2048
#define Ddim 1024
#define Edim 2048
#define CH 64
#define CL 32

#define WSCALE 32.0f   // weight fp8 pre-scale
#define XPSCALE 32.0f  // xp / gate fp8 pre-scale
#define XCSCALE 16.0f  // conv output fp8 pre-scale
#define CSCALE 16.0f   // c and u fp8 pre-scale
#define GSCALE 256.0f  // xg fp8 pre-scale

__device__ __forceinline__ void gload_lds16(const void* g, void* l) {
  __builtin_amdgcn_global_load_lds((const as1u32*)g, (as3u32*)l, 16, 0, 0);
}
__device__ __forceinline__ float sigmoidf_(float x) {
  return 1.f / (1.f + __expf(-x));
}
__device__ __forceinline__ int pk_fp8x4(float a, float b, float c, float d) {
  int p = __builtin_amdgcn_cvt_pk_fp8_f32(a, b, 0, 0);
  p = __builtin_amdgcn_cvt_pk_fp8_f32(c, d, p, 1);
  return p;
}
template<int K>
__device__ __forceinline__ float dq8(int v) {
  return __builtin_amdgcn_cvt_f32_fp8(v, K);   // K must be a front-end constant
}
__device__ __forceinline__ u8 q8(float v) {
  return (u8)(__builtin_amdgcn_cvt_pk_fp8_f32(v, v, 0, 0) & 0xff);
}

// ---------------- 3 big weight arrays fp32 -> fp8 ----------------
__global__ __launch_bounds__(256)
void cvt_fp8_3(const float* __restrict__ s0, const float* __restrict__ s1,
               const float* __restrict__ s2, u8* __restrict__ d0,
               u8* __restrict__ d1, u8* __restrict__ d2) {
  const int seg = blockIdx.x >> 12;
  const int i   = ((blockIdx.x & 4095) * 256 + threadIdx.x) * 4;
  const float* s = (seg == 0) ? s0 : (seg == 1) ? s1 : s2;
  u8*          d = (seg == 0) ? d0 : (seg == 1) ? d1 : d2;
  *(int*)(d + i) = pk_fp8x4(s[i] * WSCALE, s[i + 1] * WSCALE,
                            s[i + 2] * WSCALE, s[i + 3] * WSCALE);
}

// ---------------- generic fp32 -> fp8 (W_out) ----------------
__global__ __launch_bounds__(256)
void cvt_fp8(const float* __restrict__ s, u8* __restrict__ d, int n, float scale) {
  int i = (blockIdx.x * 256 + threadIdx.x) * 4;
  if (i < n)
    *(int*)(d + i) = pk_fp8x4(s[i] * scale, s[i + 1] * scale,
                              s[i + 2] * scale, s[i + 3] * scale);
}

// ---------------- scan scalars ----------------
__global__ __launch_bounds__(256)
void prep_scalars(const float* __restrict__ ld, const float* __restrict__ Am,
                  const float* __restrict__ Bm, float* __restrict__ aexp,
                  float* __restrict__ Ce) {
  int e = blockIdx.x * 256 + threadIdx.x;
  if (e >= Edim) return;
  float d = ld[e];
  float sp = (d > 20.f) ? d : log1pf(expf(d));
  aexp[e] = expf(-sp);
  float s = 0.f;
  #pragma unroll
  for (int n = 0; n < 16; ++n) s += Am[e * 16 + n] * Bm[e * 16 + n];
  Ce[e] = s;
}

// ---------------- layernorm -> fp8 (scale 1) ----------------
__global__ __launch_bounds__(256)
void ln_kernel(const float* __restrict__ x, const float* __restrict__ g,
               const float* __restrict__ b, u8* __restrict__ out) {
  const int row = blockIdx.x;
  const int tid = threadIdx.x;
  const float4 v = ((const float4*)(x + (size_t)row * Ddim))[tid];
  float s  = v.x + v.y + v.z + v.w;
  float ss = v.x * v.x + v.y * v.y + v.z * v.z + v.w * v.w;
  #pragma unroll
  for (int o = 32; o > 0; o >>= 1) { s += __shfl_down(s, o); ss += __shfl_down(ss, o); }
  __shared__ float sh[8];
  const int wv = tid >> 6, lane = tid & 63;
  if (lane == 0) { sh[wv] = s; sh[4 + wv] = ss; }
  __syncthreads();
  s  = sh[0] + sh[1] + sh[2] + sh[3];
  ss = sh[4] + sh[5] + sh[6] + sh[7];
  const float mean = s * (1.f / Ddim);
  const float var  = ss * (1.f / Ddim) - mean * mean;
  const float rstd = rsqrtf(var + 1e-5f);
  const float4 gv = ((const float4*)g)[tid];
  const float4 bv = ((const float4*)b)[tid];
  *(int*)(out + (size_t)row * Ddim + tid * 4) =
      pk_fp8x4((v.x - mean) * rstd * gv.x + bv.x,
               (v.y - mean) * rstd * gv.y + bv.y,
               (v.z - mean) * rstd * gv.z + bv.z,
               (v.w - mean) * rstd * gv.w + bv.w);
}

// ============ big-tile MX fp8 GEMM_BT: 256x128 block, 512 thr, BK=256 ==========
// R13's proven lever applied to the remaining GEMMs: bigger block = less staged
// L2->LDS traffic (the co-equal floor term with MFMA). 8 waves as 4Mx2N, wave
// tile 64x64 -> acc[4][4] = 64 AGPR (register-safe point: ~176 unified).
// LDS: As 64 KB + Bs 32 KB = 96 KB, 1 block/CU.
// MODE 1: Cf[idx] = v + R[idx]     MODE 3: C8[idx] = fp8( v * oscale )
template<int MODE>
__global__ __launch_bounds__(512)
void gemm_big(const u8* __restrict__ A, const u8* __restrict__ Bw,
              const float* __restrict__ bias, const float* __restrict__ R,
              u8* __restrict__ C8, float* __restrict__ Cf,
              float descale, float oscale, int M, int N, int K) {
  __shared__ __align__(16) u8 As[256 * 256];   // 64 KB
  __shared__ __align__(16) u8 Bs[128 * 256];   // 32 KB

  const int tid  = threadIdx.x;
  const int lane = tid & 63;
  const int wv   = tid >> 6;           // 0..7
  const int m0   = blockIdx.y * 256;
  const int n0   = blockIdx.x * 128;

  const int wr = (wv >> 1) * 64;       // rows 0/64/128/192
  const int wc = (wv & 1) * 64;        // cols 0/64
  const int tq = lane >> 4;
  const int tr = lane & 15;

  f32x4 acc[4][4] = {};

  // chunk = 512 thr x 16B = 8 KB = 32 rows of 256 B. A: 8 chunks; B: 4 chunks.
  const int    srow  = tid >> 4;                 // 0..31 within chunk
  const int    sc16  = tid & 15;
  const int    shalf = sc16 >> 3;
  const int    s3    = (sc16 & 7) ^ (srow & 7);
  const size_t sBase = (size_t)srow * K + shalf * 128 + s3 * 16;
  const size_t rStep = (size_t)32 * K;
  const u8* Ap = A  + (size_t)m0 * K + sBase;
  const u8* Bp = Bw + (size_t)n0 * K + sBase;
  const int ldsW = wv * 1024;

  const int s7 = tr & 7;
  const int p0 = (((tq << 1)) ^ s7) * 16;
  const int p1 = (((tq << 1) | 1) ^ s7) * 16;

  for (int k0 = 0; k0 < K; k0 += 256) {
    __syncthreads();
    #pragma unroll
    for (int g = 0; g < 8; ++g)
      gload_lds16(Ap + g * rStep + k0, (u8*)As + g * 8192 + ldsW);
    #pragma unroll
    for (int g = 0; g < 4; ++g)
      gload_lds16(Bp + g * rStep + k0, (u8*)Bs + g * 8192 + ldsW);
    __syncthreads();

    #pragma unroll
    for (int kk = 0; kk < 256; kk += 128) {
      i32x8 aF[4], bF[4];
      #pragma unroll
      for (int j = 0; j < 4; ++j) {
        const int rb = (wc + j * 16 + tr) * 256 + kk;
        const i32x4 lo = *(const i32x4*)&Bs[rb + p0];
        const i32x4 hi = *(const i32x4*)&Bs[rb + p1];
        bF[j] = __builtin_shufflevector(lo, hi, 0, 1, 2, 3, 4, 5, 6, 7);
      }
      #pragma unroll
      for (int i = 0; i < 4; ++i) {
        const int rb = (wr + i * 16 + tr) * 256 + kk;
        const i32x4 lo = *(const i32x4*)&As[rb + p0];
        const i32x4 hi = *(const i32x4*)&As[rb + p1];
        aF[i] = __builtin_shufflevector(lo, hi, 0, 1, 2, 3, 4, 5, 6, 7);
      }
      #pragma unroll
      for (int i = 0; i < 4; ++i)
        #pragma unroll
        for (int j = 0; j < 4; ++j)
          acc[i][j] = __builtin_amdgcn_mfma_scale_f32_16x16x128_f8f6f4(
              aF[i], bF[j], acc[i][j], 0, 0, 0, 0x7F, 0, 0x7F);
    }
  }

  #pragma unroll
  for (int i = 0; i < 4; ++i) {
    #pragma unroll
    for (int j = 0; j < 4; ++j) {
      const int col = n0 + wc + j * 16 + tr;
      const float bv = bias[col];
      #pragma unroll
      for (int r = 0; r < 4; ++r) {
        const int rowg = m0 + wr + i * 16 + tq * 4 + r;
        const size_t idx = (size_t)rowg * N + col;
        const float v = acc[i][j][r] * descale + bv;
        if (MODE == 1) {
          Cf[idx] = v + R[idx];
        } else {
          C8[idx] = q8(v * oscale);
        }
      }
    }
  }
}

// ============ fused c/u GEMM: 256x128 block, 512 thr (8 waves 4Mx2N) ===========
// u = (A@Wc^T+bc)*sigmoid(A@Wd^T+bd). Wave tile 64x64 -> accC+accD = 64 AGPR.
// BK=256, single-buffered: As 64 KB + Bs 64 KB (128 Wc rows + 128 Wd rows)
// = 128 KB, 1 block/CU. (R13: 66.2 us; at its LDS ceiling — BN=256 needs 192 KB.)
__global__ __launch_bounds__(512)
void gemm_cu(const u8* __restrict__ A, const u8* __restrict__ Wc8,
             const u8* __restrict__ Wd8, const float* __restrict__ bias_c,
             const float* __restrict__ bias_d, u8* __restrict__ U8,
             float descale, int M, int N, int K) {
  __shared__ __align__(16) u8 As[256 * 256];   // 64 KB
  __shared__ __align__(16) u8 Bs[256 * 256];   // 64 KB: rows 0-127 Wc, 128-255 Wd

  const int tid  = threadIdx.x;
  const int lane = tid & 63;
  const int wv   = tid >> 6;           // 0..7
  const int m0   = blockIdx.y * 256;
  const int n0   = blockIdx.x * 128;

  const int wr = (wv >> 1) * 64;       // rows 0/64/128/192
  const int wc = (wv & 1) * 64;        // cols 0/64
  const int tq = lane >> 4;
  const int tr = lane & 15;

  f32x4 accC[4][2] = {};
  f32x4 accD[4][2] = {};

  // chunk = 512 thr x 16B = 8 KB = 32 rows of 256 B. A: 8 chunks; Wc 4; Wd 4.
  const int    srow  = tid >> 4;                 // 0..31 within chunk
  const int    sc16  = tid & 15;
  const int    shalf = sc16 >> 3;
  const int    s3    = (sc16 & 7) ^ (srow & 7);
  const size_t sBase = (size_t)srow * K + shalf * 128 + s3 * 16;
  const size_t rStep = (size_t)32 * K;           // rows per chunk
  const u8* Ap = A   + (size_t)m0 * K + sBase;
  const u8* Cp = Wc8 + (size_t)n0 * K + sBase;
  const u8* Dp = Wd8 + (size_t)n0 * K + sBase;
  const int ldsW = wv * 1024;                    // 8 waves x 1 KB = 8 KB/chunk

  const int s7 = tr & 7;
  const int p0 = (((tq << 1)) ^ s7) * 16;
  const int p1 = (((tq << 1) | 1) ^ s7) * 16;

  for (int k0 = 0; k0 < K; k0 += 256) {
    __syncthreads();
    #pragma unroll
    for (int g = 0; g < 8; ++g)
      gload_lds16(Ap + g * rStep + k0, (u8*)As + g * 8192 + ldsW);
    #pragma unroll
    for (int g = 0; g < 4; ++g)
      gload_lds16(Cp + g * rStep + k0, (u8*)Bs + g * 8192 + ldsW);
    #pragma unroll
    for (int g = 0; g < 4; ++g)
      gload_lds16(Dp + g * rStep + k0, (u8*)Bs + 32768 + g * 8192 + ldsW);
    __syncthreads();

    #pragma unroll
    for (int kk = 0; kk < 256; kk += 128) {
      i32x8 aF[4], bC[2], bD[2];
      #pragma unroll
      for (int j = 0; j < 2; ++j) {
        const int rbc = (wc + j * 16 + tr) * 256 + kk;
        const i32x4 loc = *(const i32x4*)&Bs[rbc + p0];
        const i32x4 hic = *(const i32x4*)&Bs[rbc + p1];
        bC[j] = __builtin_shufflevector(loc, hic, 0, 1, 2, 3, 4, 5, 6, 7);
        const int rbd = (128 + wc + j * 16 + tr) * 256 + kk;
        const i32x4 lod = *(const i32x4*)&Bs[rbd + p0];
        const i32x4 hid = *(const i32x4*)&Bs[rbd + p1];
        bD[j] = __builtin_shufflevector(lod, hid, 0, 1, 2, 3, 4, 5, 6, 7);
      }
      #pragma unroll
      for (int i = 0; i < 4; ++i) {
        const int rb = (wr + i * 16 + tr) * 256 + kk;
        const i32x4 lo = *(const i32x4*)&As[rb + p0];
        const i32x4 hi = *(const i32x4*)&As[rb + p1];
        aF[i] = __builtin_shufflevector(lo, hi, 0, 1, 2, 3, 4, 5, 6, 7);
      }
      #pragma unroll
      for (int i = 0; i < 4; ++i)
        #pragma unroll
        for (int j = 0; j < 2; ++j) {
          accC[i][j] = __builtin_amdgcn_mfma_scale_f32_16x16x128_f8f6f4(
              aF[i], bC[j], accC[i][j], 0, 0, 0, 0x7F, 0, 0x7F);
          accD[i][j] = __builtin_amdgcn_mfma_scale_f32_16x16x128_f8f6f4(
              aF[i], bD[j], accD[i][j], 0, 0, 0, 0x7F, 0, 0x7F);
        }
    }
  }

  #pragma unroll
  for (int i = 0; i < 4; ++i) {
    #pragma unroll
    for (int j = 0; j < 2; ++j) {
      const int col = n0 + wc + j * 16 + tr;
      const float bc = bias_c[col];
      const float bd = bias_d[col];
      #pragma unroll
      for (int r = 0; r < 4; ++r) {
        const int rowg = m0 + wr + i * 16 + tq * 4 + r;
        const size_t idx = (size_t)rowg * N + col;
        const float vc = accC[i][j][r] * descale + bc;
        const float vd = accD[i][j][r] * descale + bd;
        U8[idx] = q8(vc * CSCALE * sigmoidf_(vd));   // = u * CSCALE
      }
    }
  }
}

// ---------------- causal depthwise conv (K=4) + silu, fp8 in/out, 4 e/thread ----
__global__ __launch_bounds__(256)
void conv_silu(const u8* __restrict__ xpg8, const float* __restrict__ cw,
               const float* __restrict__ cb, u8* __restrict__ xc8) {
  const int e0 = (blockIdx.y * 256 + threadIdx.x) * 4;   // gridDim.y = Edim/1024
  const int b  = blockIdx.x >> 9;
  const int s0 = (blockIdx.x & 511) * 4;
  float w[4][4], bias[4];
  #pragma unroll
  for (int k = 0; k < 4; ++k) {
    const float4 wv = *(const float4*)(cw + (e0 + k) * 4);
    w[k][0] = wv.x; w[k][1] = wv.y; w[k][2] = wv.z; w[k][3] = wv.w;
    bias[k] = cb[e0 + k];
  }
  float f[7][4];
  #pragma unroll
  for (int j = 0; j < 7; ++j) {
    const int s = s0 - 3 + j;
    const int xv = (s >= 0) ? *(const int*)(xpg8 + (size_t)(b * Sdim + s) * (2 * Edim) + e0) : 0;
    f[j][0] = dq8<0>(xv); f[j][1] = dq8<1>(xv);
    f[j][2] = dq8<2>(xv); f[j][3] = dq8<3>(xv);
  }
  #pragma unroll
  for (int t = 0; t < 4; ++t) {
    float y[4];
    #pragma unroll
    for (int k = 0; k < 4; ++k) {
      float a = fmaf(w[k][0], f[t][k],
               fmaf(w[k][1], f[t + 1][k],
               fmaf(w[k][2], f[t + 2][k],
                    w[k][3] * f[t + 3][k])));
      a = a * (1.f / XPSCALE) + bias[k];
      y[k] = a * sigmoidf_(a) * XCSCALE;
    }
    *(int*)(xc8 + (size_t)(b * Sdim + s0 + t) * Edim + e0) =
        pk_fp8x4(y[0], y[1], y[2], y[3]);
  }
}

// ---------------- chunked parallel scan (fp8 u, 4 e/thread) ----------------
// z is kept in u-scaled units (x CSCALE); part2 is linear so unaffected.
__global__ __launch_bounds__(256)
void scan_part1(const u8* __restrict__ u8p, const float* __restrict__ aexp,
                float* __restrict__ zloc) {
  const int c  = blockIdx.x;
  const int b  = blockIdx.y >> 1;
  const int e0 = ((blockIdx.y & 1) * 256 + threadIdx.x) * 4;
  const float4 av = *(const float4*)(aexp + e0);
  const u8* up = u8p + ((size_t)(b * Sdim + c * CL)) * Edim + e0;
  float z0 = 0.f, z1 = 0.f, z2 = 0.f, z3 = 0.f;
  #pragma unroll
  for (int t = 0; t < CL; ++t) {
    const int uv = *(const int*)(up + (size_t)t * Edim);
    z0 = fmaf(av.x, z0, dq8<0>(uv));
    z1 = fmaf(av.y, z1, dq8<1>(uv));
    z2 = fmaf(av.z, z2, dq8<2>(uv));
    z3 = fmaf(av.w, z3, dq8<3>(uv));
  }
  float4 zv = {z0, z1, z2, z3};
  *(float4*)(zloc + ((size_t)b * CH + c) * Edim + e0) = zv;
}

__global__ __launch_bounds__(256)
void scan_part2(const float* __restrict__ aexp, float* __restrict__ zloc) {
  const int idx = blockIdx.x * 256 + threadIdx.x;
  const int b = idx >> 11, e = idx & (Edim - 1);
  float a  = aexp[e];
  float aL = a * a;
  aL = aL * aL; aL = aL * aL; aL = aL * aL; aL = aL * aL;  // a^32
  float* zp = zloc + (size_t)b * CH * Edim + e;
  float pref = 0.f;
  #pragma unroll 4
  for (int c = 0; c < CH; ++c) {
    const float loc = zp[(size_t)c * Edim];
    zp[(size_t)c * Edim] = pref;
    pref = fmaf(aL, pref, loc);
  }
}

// Phase 3: re-scan, gate, write xg fp8.  y*GSCALE = Ce*(z/CSCALE)*sig*GSCALE
__global__ __launch_bounds__(256)
void scan_part3(const u8* __restrict__ u8p, const u8* __restrict__ xpg8,
                const float* __restrict__ aexp, const float* __restrict__ Ce,
                const float* __restrict__ zloc, u8* __restrict__ xg8) {
  const int c  = blockIdx.x;
  const int b  = blockIdx.y >> 1;
  const int e0 = ((blockIdx.y & 1) * 256 + threadIdx.x) * 4;
  const float4 av = *(const float4*)(aexp + e0);
  float4 Cv = *(const float4*)(Ce + e0);
  const float cs = GSCALE / CSCALE;
  Cv.x *= cs; Cv.y *= cs; Cv.z *= cs; Cv.w *= cs;
  float4 zv = *(const float4*)(zloc + ((size_t)b * CH + c) * Edim + e0);
  const u8* up = u8p  + ((size_t)(b * Sdim + c * CL)) * Edim + e0;
  const u8* gp = xpg8 + ((size_t)(b * Sdim + c * CL)) * (2 * Edim) + Edim + e0;
  u8*       op = xg8  + ((size_t)(b * Sdim + c * CL)) * Edim + e0;
  #pragma unroll 4
  for (int t = 0; t < CL; ++t) {
    const int uv = *(const int*)(up + (size_t)t * Edim);
    const int gv = *(const int*)(gp + (size_t)t * (2 * Edim));
    zv.x = fmaf(av.x, zv.x, dq8<0>(uv));
    zv.y = fmaf(av.y, zv.y, dq8<1>(uv));
    zv.z = fmaf(av.z, zv.z, dq8<2>(uv));
    zv.w = fmaf(av.w, zv.w, dq8<3>(uv));
    const float y0 = Cv.x * zv.x * sigmoidf_(dq8<0>(gv) * (1.f / XPSCALE));
    const float y1 = Cv.y * zv.y * sigmoidf_(dq8<1>(gv) * (1.f / XPSCALE));
    const float y2 = Cv.z * zv.z * sigmoidf_(dq8<2>(gv) * (1.f / XPSCALE));
    const float y3 = Cv.w * zv.w * sigmoidf_(dq8<3>(gv) * (1.f / XPSCALE));
    *(int*)(op + (size_t)t * Edim) = pk_fp8x4(y0, y1, y2, y3);
  }
}

extern "C" void kernel_launch(void* const* d_in, const int* in_sizes, int n_in,
                              void* d_out, int out_size, void* d_ws, size_t ws_size,
                              hipStream_t stream) {
  const float* x         = (const float*)d_in[0];
  const float* ln_g      = (const float*)d_in[1];
  const float* ln_b      = (const float*)d_in[2];
  const float* W_in      = (const float*)d_in[3];
  const float* b_in      = (const float*)d_in[4];
  const float* conv_w    = (const float*)d_in[5];
  const float* conv_b    = (const float*)d_in[6];
  const float* Am        = (const float*)d_in[7];
  const float* Bm        = (const float*)d_in[8];
  const float* W_c       = (const float*)d_in[9];
  const float* b_c       = (const float*)d_in[10];
  const float* W_d       = (const float*)d_in[11];
  const float* b_d       = (const float*)d_in[12];
  const float* log_delta = (const float*)d_in[13];
  const float* W_out     = (const float*)d_in[14];
  const float* b_out     = (const float*)d_in[15];
  float* out = (float*)d_out;

  const size_t MiB = 1024 * 1024;
  char* w = (char*)d_ws;
  u8*     wWin8  = (u8*)   (w + 0);             //  4 MiB
  u8*     wWc8   = (u8*)   (w + 4 * MiB);       //  4 MiB
  u8*     wWd8   = (u8*)   (w + 8 * MiB);       //  4 MiB
  u8*     wWout8 = (u8*)   (w + 12 * MiB);      //  2 MiB
  float*  aexp   = (float*)(w + 15 * MiB);
  float*  Ce     = (float*)(w + 15 * MiB + 16384);
  float*  zloc   = (float*)(w + 15 * MiB + 65536);  // 2 MiB
  u8*     xln8   = (u8*)   (w + 18 * MiB);      //  8 MiB (8192x1024)
  u8*     xpg8   = (u8*)   (w + 26 * MiB);      // 32 MiB (8192x4096)
  u8*     xc8    = (u8*)   (w + 58 * MiB);      // 16 MiB
  u8*     u8b    = (u8*)   (w + 90 * MiB);      // 16 MiB
  u8*     xg8    = (u8*)   (w + 106 * MiB);     // 16 MiB -> 122 MiB

  const int M = Bdim * Sdim;  // 8192
  const float dsIn  = 1.f / WSCALE;
  const float dsCD  = 1.f / (WSCALE * XCSCALE);
  const float dsOut = 1.f / (WSCALE * GSCALE);

  cvt_fp8_3<<<3 * 4096, 256, 0, stream>>>(W_in, W_c, W_d, wWin8, wWc8, wWd8);
  cvt_fp8<<<(Ddim * Edim) / 1024, 256, 0, stream>>>(W_out, wWout8, Ddim * Edim, WSCALE);
  prep_scalars<<<Edim / 256, 256, 0, stream>>>(log_delta, Am, Bm, aexp, Ce);

  ln_kernel<<<M, 256, 0, stream>>>(x, ln_g, ln_b, xln8);

  // xpg = fp8( (x_ln @ W_in^T + b_in) * XPSCALE )  — 256x128 big tile
  gemm_big<3><<<dim3((2 * Edim) / 128, M / 256), 512, 0, stream>>>(
      xln8, wWin8, b_in, nullptr, xpg8, nullptr, dsIn, XPSCALE, M, 2 * Edim, Ddim);

  conv_silu<<<dim3(Bdim * (Sdim / 4), Edim / 1024), 256, 0, stream>>>(xpg8, conv_w, conv_b, xc8);

  // u8b = fp8( (xc@Wc^T+bc) * sigmoid(xc@Wd^T+bd) * CSCALE )  — fused, 256x128
  gemm_cu<<<dim3(Edim / 128, M / 256), 512, 0, stream>>>(
      xc8, wWc8, wWd8, b_c, b_d, u8b, dsCD, M, Edim, Edim);

  scan_part1<<<dim3(CH, Bdim * 2), 256, 0, stream>>>(u8b, aexp, zloc);
  scan_part2<<<(Bdim * Edim) / 256, 256, 0, stream>>>(aexp, zloc);
  scan_part3<<<dim3(CH, Bdim * 2), 256, 0, stream>>>(u8b, xpg8, aexp, Ce, zloc, xg8);

  // out = xg @ W_out^T + b_out + x  — 256x128 big tile, grid = 256 = 1 blk/CU
  gemm_big<1><<<dim3(Ddim / 128, M / 256), 512, 0, stream>>>(
      xg8, wWout8, b_out, x, nullptr, out, dsOut, 1.f, M, Ddim, Edim);

  (void)in_sizes; (void)n_in; (void)out_size; (void)ws_size;
}

// Round 15
// 333.516 us; speedup vs baseline: 1.0958x; 1.0958x over previous
//
#include <hip/hip_runtime.h>
#include <hip/hip_bf16.h>

typedef __bf16 bf16_t;
typedef unsigned char u8;
typedef float  f32x4  __attribute__((ext_vector_type(4)));
typedef int    i32x4  __attribute__((ext_vector_type(4)));
typedef int    i32x8  __attribute__((ext_vector_type(8)));
typedef __attribute__((address_space(3))) unsigned as3u32;
typedef __attribute__((address_space(1))) unsigned as1u32;

#define Bdim 4
#define Sdim 2048
#define Ddim 1024
#define Edim 2048
#define CH 64
#define CL 32

#define WSCALE 32.0f   // weight fp8 pre-scale
#define XPSCALE 32.0f  // xp / gate fp8 pre-scale
#define XCSCALE 16.0f  // conv output fp8 pre-scale
#define CSCALE 16.0f   // c and u fp8 pre-scale
#define GSCALE 256.0f  // xg fp8 pre-scale

__device__ __forceinline__ void gload_lds16(const void* g, void* l) {
  __builtin_amdgcn_global_load_lds((const as1u32*)g, (as3u32*)l, 16, 0, 0);
}
__device__ __forceinline__ float sigmoidf_(float x) {
  return 1.f / (1.f + __expf(-x));
}
__device__ __forceinline__ int pk_fp8x4(float a, float b, float c, float d) {
  int p = __builtin_amdgcn_cvt_pk_fp8_f32(a, b, 0, 0);
  p = __builtin_amdgcn_cvt_pk_fp8_f32(c, d, p, 1);
  return p;
}
template<int K>
__device__ __forceinline__ float dq8(int v) {
  return __builtin_amdgcn_cvt_f32_fp8(v, K);   // K must be a front-end constant
}
__device__ __forceinline__ u8 q8(float v) {
  return (u8)(__builtin_amdgcn_cvt_pk_fp8_f32(v, v, 0, 0) & 0xff);
}

// ---------------- 3 big weight arrays fp32 -> fp8 ----------------
__global__ __launch_bounds__(256)
void cvt_fp8_3(const float* __restrict__ s0, const float* __restrict__ s1,
               const float* __restrict__ s2, u8* __restrict__ d0,
               u8* __restrict__ d1, u8* __restrict__ d2) {
  const int seg = blockIdx.x >> 12;
  const int i   = ((blockIdx.x & 4095) * 256 + threadIdx.x) * 4;
  const float* s = (seg == 0) ? s0 : (seg == 1) ? s1 : s2;
  u8*          d = (seg == 0) ? d0 : (seg == 1) ? d1 : d2;
  *(int*)(d + i) = pk_fp8x4(s[i] * WSCALE, s[i + 1] * WSCALE,
                            s[i + 2] * WSCALE, s[i + 3] * WSCALE);
}

// ---------------- generic fp32 -> fp8 (W_out) ----------------
__global__ __launch_bounds__(256)
void cvt_fp8(const float* __restrict__ s, u8* __restrict__ d, int n, float scale) {
  int i = (blockIdx.x * 256 + threadIdx.x) * 4;
  if (i < n)
    *(int*)(d + i) = pk_fp8x4(s[i] * scale, s[i + 1] * scale,
                              s[i + 2] * scale, s[i + 3] * scale);
}

// ---------------- scan scalars ----------------
__global__ __launch_bounds__(256)
void prep_scalars(const float* __restrict__ ld, const float* __restrict__ Am,
                  const float* __restrict__ Bm, float* __restrict__ aexp,
                  float* __restrict__ Ce) {
  int e = blockIdx.x * 256 + threadIdx.x;
  if (e >= Edim) return;
  float d = ld[e];
  float sp = (d > 20.f) ? d : log1pf(expf(d));
  aexp[e] = expf(-sp);
  float s = 0.f;
  #pragma unroll
  for (int n = 0; n < 16; ++n) s += Am[e * 16 + n] * Bm[e * 16 + n];
  Ce[e] = s;
}

// ---------------- layernorm -> fp8 (scale 1) ----------------
__global__ __launch_bounds__(256)
void ln_kernel(const float* __restrict__ x, const float* __restrict__ g,
               const float* __restrict__ b, u8* __restrict__ out) {
  const int row = blockIdx.x;
  const int tid = threadIdx.x;
  const float4 v = ((const float4*)(x + (size_t)row * Ddim))[tid];
  float s  = v.x + v.y + v.z + v.w;
  float ss = v.x * v.x + v.y * v.y + v.z * v.z + v.w * v.w;
  #pragma unroll
  for (int o = 32; o > 0; o >>= 1) { s += __shfl_down(s, o); ss += __shfl_down(ss, o); }
  __shared__ float sh[8];
  const int wv = tid >> 6, lane = tid & 63;
  if (lane == 0) { sh[wv] = s; sh[4 + wv] = ss; }
  __syncthreads();
  s  = sh[0] + sh[1] + sh[2] + sh[3];
  ss = sh[4] + sh[5] + sh[6] + sh[7];
  const float mean = s * (1.f / Ddim);
  const float var  = ss * (1.f / Ddim) - mean * mean;
  const float rstd = rsqrtf(var + 1e-5f);
  const float4 gv = ((const float4*)g)[tid];
  const float4 bv = ((const float4*)b)[tid];
  *(int*)(out + (size_t)row * Ddim + tid * 4) =
      pk_fp8x4((v.x - mean) * rstd * gv.x + bv.x,
               (v.y - mean) * rstd * gv.y + bv.y,
               (v.z - mean) * rstd * gv.z + bv.z,
               (v.w - mean) * rstd * gv.w + bv.w);
}

// ============ MX fp8 GEMM_BT: 128x128 tile, BK=256, mfma_scale 16x16x128 =========
// acc = A8 @ B8^T; v = acc*descale + bias.
// MODE 1: Cf[idx] = v + R[idx]     MODE 3: C8[idx] = fp8( v * oscale )
// Register-safe: acc 64 AGPR + ~112 arch -> 2 blocks/CU (cross-block overlap —
// R14 lesson: big tiles regress here because K is shallow, 4-8 iters).
#define BM 128
#define BN 128

template<int MODE>
__global__ __launch_bounds__(256)
void gemm_mx(const u8* __restrict__ A, const u8* __restrict__ Bw,
             const float* __restrict__ bias, const u8* __restrict__ X,
             const float* __restrict__ R, u8* __restrict__ C8,
             float* __restrict__ Cf, float descale, float oscale,
             int M, int N, int K) {
  __shared__ __align__(16) u8 As[BM * 256];   // 32 KB
  __shared__ __align__(16) u8 Bs[BN * 256];   // 32 KB

  const int tid  = threadIdx.x;
  const int lane = tid & 63;
  const int wv   = tid >> 6;
  const int m0   = blockIdx.y * BM;
  const int n0   = blockIdx.x * BN;

  const int wr = (wv >> 1) * 64;
  const int wc = (wv & 1) * 64;
  const int tq = lane >> 4;
  const int tr = lane & 15;

  f32x4 acc[4][4] = {};

  // chunk = 256 thr x 16B = 4 KB = 16 rows of 256 B. 8 chunks per matrix.
  const int    srow  = tid >> 4;                 // 0..15 within chunk
  const int    sc16  = tid & 15;                 // 16B slot 0..15
  const int    shalf = sc16 >> 3;                // which 128B half
  const int    s3    = (sc16 & 7) ^ (srow & 7);  // swizzled slot in half
  const size_t sBase = (size_t)srow * K + shalf * 128 + s3 * 16;
  const size_t rStep = (size_t)16 * K;           // rows per chunk
  const u8* Ap = A  + (size_t)m0 * K + sBase;
  const u8* Bp = Bw + (size_t)n0 * K + sBase;
  const int ldsW = wv * 1024;

  const int s7 = tr & 7;
  const int p0 = (((tq << 1)) ^ s7) * 16;
  const int p1 = (((tq << 1) | 1) ^ s7) * 16;

  for (int k0 = 0; k0 < K; k0 += 256) {
    __syncthreads();
    #pragma unroll
    for (int g = 0; g < 8; ++g)
      gload_lds16(Ap + g * rStep + k0, (u8*)As + g * 4096 + ldsW);
    #pragma unroll
    for (int g = 0; g < 8; ++g)
      gload_lds16(Bp + g * rStep + k0, (u8*)Bs + g * 4096 + ldsW);
    __syncthreads();

    #pragma unroll
    for (int kk = 0; kk < 256; kk += 128) {
      i32x8 aF[4], bF[4];
      #pragma unroll
      for (int i = 0; i < 4; ++i) {
        const int rb = (wr + i * 16 + tr) * 256 + kk;
        const i32x4 lo = *(const i32x4*)&As[rb + p0];
        const i32x4 hi = *(const i32x4*)&As[rb + p1];
        aF[i] = __builtin_shufflevector(lo, hi, 0, 1, 2, 3, 4, 5, 6, 7);
      }
      #pragma unroll
      for (int j = 0; j < 4; ++j) {
        const int rb = (wc + j * 16 + tr) * 256 + kk;
        const i32x4 lo = *(const i32x4*)&Bs[rb + p0];
        const i32x4 hi = *(const i32x4*)&Bs[rb + p1];
        bF[j] = __builtin_shufflevector(lo, hi, 0, 1, 2, 3, 4, 5, 6, 7);
      }
      #pragma unroll
      for (int i = 0; i < 4; ++i)
        #pragma unroll
        for (int j = 0; j < 4; ++j)
          acc[i][j] = __builtin_amdgcn_mfma_scale_f32_16x16x128_f8f6f4(
              aF[i], bF[j], acc[i][j], 0, 0, 0, 0x7F, 0, 0x7F);
    }
  }

  #pragma unroll
  for (int i = 0; i < 4; ++i) {
    #pragma unroll
    for (int j = 0; j < 4; ++j) {
      const int col = n0 + wc + j * 16 + tr;
      const float bv = bias[col];
      #pragma unroll
      for (int r = 0; r < 4; ++r) {
        const int rowg = m0 + wr + i * 16 + tq * 4 + r;
        const size_t idx = (size_t)rowg * N + col;
        const float v = acc[i][j][r] * descale + bv;
        if (MODE == 1) {
          Cf[idx] = v + R[idx];
        } else {
          C8[idx] = q8(v * oscale);
        }
      }
    }
  }
}

// ============ fused c/u GEMM: 256x128 block, 512 thr, BK=128 DOUBLE-BUFFERED ====
// u = (A@Wc^T+bc)*sigmoid(A@Wd^T+bd). R13 measured this kernel at 1 block/CU as
// fully SERIAL: MFMA 29.5 + LDS-read 20.5 + staging-DMA 15 ~= 66 us. With ONE
// block/CU there is no implicit cross-block overlap (why R12's dbuf was null at
// 2 blk/CU but should pay here): static dual buffers (4 x 32 KB = same 128 KB),
// per tile {ds_read; setprio MFMA; barrier; stage t+2 into just-freed buffer;
// vmcnt(8) — drains t+1's 8 loads, leaves t+2's in flight; barrier}. Staging
// then hides under compute: per-iter ~ max(LDS-port, MFMA) not the sum.
// Wave tile 64x64 -> accC+accD = 64 AGPR, ~112 arch VGPR.
#define CUT2(AS, BS, t_)                                                       \
  {                                                                            \
    i32x8 aF[4], bC[2], bD[2];                                                 \
    _Pragma("unroll") for (int j_ = 0; j_ < 2; ++j_) {                         \
      const int rbc = (wc + j_ * 16 + tr) * 128;                               \
      const i32x4 loc = *(const i32x4*)&(BS)[rbc + p0];                        \
      const i32x4 hic = *(const i32x4*)&(BS)[rbc + p1];                        \
      bC[j_] = __builtin_shufflevector(loc, hic, 0, 1, 2, 3, 4, 5, 6, 7);      \
      const int rbd = (128 + wc + j_ * 16 + tr) * 128;                         \
      const i32x4 lod = *(const i32x4*)&(BS)[rbd + p0];                        \
      const i32x4 hid = *(const i32x4*)&(BS)[rbd + p1];                        \
      bD[j_] = __builtin_shufflevector(lod, hid, 0, 1, 2, 3, 4, 5, 6, 7);      \
    }                                                                          \
    _Pragma("unroll") for (int i_ = 0; i_ < 4; ++i_) {                         \
      const int rb = (wr + i_ * 16 + tr) * 128;                                \
      const i32x4 lo = *(const i32x4*)&(AS)[rb + p0];                          \
      const i32x4 hi = *(const i32x4*)&(AS)[rb + p1];                          \
      aF[i_] = __builtin_shufflevector(lo, hi, 0, 1, 2, 3, 4, 5, 6, 7);        \
    }                                                                          \
    __builtin_amdgcn_s_setprio(1);                                             \
    _Pragma("unroll") for (int i_ = 0; i_ < 4; ++i_)                           \
      _Pragma("unroll") for (int j_ = 0; j_ < 2; ++j_) {                       \
        accC[i_][j_] = __builtin_amdgcn_mfma_scale_f32_16x16x128_f8f6f4(       \
            aF[i_], bC[j_], accC[i_][j_], 0, 0, 0, 0x7F, 0, 0x7F);             \
        accD[i_][j_] = __builtin_amdgcn_mfma_scale_f32_16x16x128_f8f6f4(       \
            aF[i_], bD[j_], accD[i_][j_], 0, 0, 0, 0x7F, 0, 0x7F);             \
      }                                                                        \
    __builtin_amdgcn_s_setprio(0);                                             \
    __builtin_amdgcn_s_barrier();                                              \
    if ((t_) + 2 < NK) {                                                       \
      const size_t ko_ = (size_t)((t_) + 2) * 128;                             \
      _Pragma("unroll") for (int g_ = 0; g_ < 4; ++g_)                         \
        gload_lds16(Ap + g_ * rStep + ko_, (u8*)(AS) + g_ * 8192 + ldsW);      \
      _Pragma("unroll") for (int g_ = 0; g_ < 2; ++g_)                         \
        gload_lds16(Cp + g_ * rStep + ko_, (u8*)(BS) + g_ * 8192 + ldsW);      \
      _Pragma("unroll") for (int g_ = 0; g_ < 2; ++g_)                         \
        gload_lds16(Dp + g_ * rStep + ko_, (u8*)(BS) + 16384 + g_ * 8192 + ldsW); \
      asm volatile("s_waitcnt vmcnt(8)" ::: "memory");                         \
    } else {                                                                   \
      asm volatile("s_waitcnt vmcnt(0)" ::: "memory");                         \
    }                                                                          \
    __builtin_amdgcn_s_barrier();                                              \
  }

__global__ __launch_bounds__(512)
void gemm_cu(const u8* __restrict__ A, const u8* __restrict__ Wc8,
             const u8* __restrict__ Wd8, const float* __restrict__ bias_c,
             const float* __restrict__ bias_d, u8* __restrict__ U8,
             float descale, int M, int N, int K) {
  __shared__ __align__(16) u8 As0[256 * 128];  // 32 KB
  __shared__ __align__(16) u8 Bs0[256 * 128];  // 32 KB: 128 Wc rows + 128 Wd rows
  __shared__ __align__(16) u8 As1[256 * 128];
  __shared__ __align__(16) u8 Bs1[256 * 128];

  const int tid  = threadIdx.x;
  const int lane = tid & 63;
  const int wv   = tid >> 6;           // 0..7
  const int m0   = blockIdx.y * 256;
  const int n0   = blockIdx.x * 128;

  const int wr = (wv >> 1) * 64;       // rows 0/64/128/192
  const int wc = (wv & 1) * 64;        // cols 0/64
  const int tq = lane >> 4;
  const int tr = lane & 15;

  f32x4 accC[4][2] = {};
  f32x4 accD[4][2] = {};

  // chunk = 512 thr x 16B = 8 KB = 64 rows of 128 B. A: 4 chunks; Wc 2; Wd 2.
  const int    srow = tid >> 3;                  // 0..63 within chunk
  const int    scol = (tid & 7) ^ (srow & 7);
  const size_t sBase = (size_t)srow * K + (size_t)scol * 16;
  const size_t rStep = (size_t)64 * K;           // rows per chunk
  const u8* Ap = A   + (size_t)m0 * K + sBase;
  const u8* Cp = Wc8 + (size_t)n0 * K + sBase;
  const u8* Dp = Wd8 + (size_t)n0 * K + sBase;
  const int ldsW = wv * 1024;                    // 8 waves x 1 KB = 8 KB/chunk

  const int s7 = tr & 7;
  const int p0 = (((tq << 1)) ^ s7) * 16;
  const int p1 = (((tq << 1) | 1) ^ s7) * 16;

  const int NK = K >> 7;   // 16

  // prologue: tile 0 -> buf0, tile 1 -> buf1; wait tile0 (tile1 in flight)
  #pragma unroll
  for (int g = 0; g < 4; ++g)
    gload_lds16(Ap + g * rStep, (u8*)As0 + g * 8192 + ldsW);
  #pragma unroll
  for (int g = 0; g < 2; ++g)
    gload_lds16(Cp + g * rStep, (u8*)Bs0 + g * 8192 + ldsW);
  #pragma unroll
  for (int g = 0; g < 2; ++g)
    gload_lds16(Dp + g * rStep, (u8*)Bs0 + 16384 + g * 8192 + ldsW);
  #pragma unroll
  for (int g = 0; g < 4; ++g)
    gload_lds16(Ap + g * rStep + 128, (u8*)As1 + g * 8192 + ldsW);
  #pragma unroll
  for (int g = 0; g < 2; ++g)
    gload_lds16(Cp + g * rStep + 128, (u8*)Bs1 + g * 8192 + ldsW);
  #pragma unroll
  for (int g = 0; g < 2; ++g)
    gload_lds16(Dp + g * rStep + 128, (u8*)Bs1 + 16384 + g * 8192 + ldsW);
  asm volatile("s_waitcnt vmcnt(8)" ::: "memory");
  __builtin_amdgcn_s_barrier();

  for (int tp = 0; tp < (NK >> 1); ++tp) {
    const int t0 = tp * 2;
    CUT2(As0, Bs0, t0);
    CUT2(As1, Bs1, t0 + 1);
  }

  #pragma unroll
  for (int i = 0; i < 4; ++i) {
    #pragma unroll
    for (int j = 0; j < 2; ++j) {
      const int col = n0 + wc + j * 16 + tr;
      const float bc = bias_c[col];
      const float bd = bias_d[col];
      #pragma unroll
      for (int r = 0; r < 4; ++r) {
        const int rowg = m0 + wr + i * 16 + tq * 4 + r;
        const size_t idx = (size_t)rowg * N + col;
        const float vc = accC[i][j][r] * descale + bc;
        const float vd = accD[i][j][r] * descale + bd;
        U8[idx] = q8(vc * CSCALE * sigmoidf_(vd));   // = u * CSCALE
      }
    }
  }
}

// ---------------- causal depthwise conv (K=4) + silu, fp8 in/out, 4 e/thread ----
__global__ __launch_bounds__(256)
void conv_silu(const u8* __restrict__ xpg8, const float* __restrict__ cw,
               const float* __restrict__ cb, u8* __restrict__ xc8) {
  const int e0 = (blockIdx.y * 256 + threadIdx.x) * 4;   // gridDim.y = Edim/1024
  const int b  = blockIdx.x >> 9;
  const int s0 = (blockIdx.x & 511) * 4;
  float w[4][4], bias[4];
  #pragma unroll
  for (int k = 0; k < 4; ++k) {
    const float4 wv = *(const float4*)(cw + (e0 + k) * 4);
    w[k][0] = wv.x; w[k][1] = wv.y; w[k][2] = wv.z; w[k][3] = wv.w;
    bias[k] = cb[e0 + k];
  }
  float f[7][4];
  #pragma unroll
  for (int j = 0; j < 7; ++j) {
    const int s = s0 - 3 + j;
    const int xv = (s >= 0) ? *(const int*)(xpg8 + (size_t)(b * Sdim + s) * (2 * Edim) + e0) : 0;
    f[j][0] = dq8<0>(xv); f[j][1] = dq8<1>(xv);
    f[j][2] = dq8<2>(xv); f[j][3] = dq8<3>(xv);
  }
  #pragma unroll
  for (int t = 0; t < 4; ++t) {
    float y[4];
    #pragma unroll
    for (int k = 0; k < 4; ++k) {
      float a = fmaf(w[k][0], f[t][k],
               fmaf(w[k][1], f[t + 1][k],
               fmaf(w[k][2], f[t + 2][k],
                    w[k][3] * f[t + 3][k])));
      a = a * (1.f / XPSCALE) + bias[k];
      y[k] = a * sigmoidf_(a) * XCSCALE;
    }
    *(int*)(xc8 + (size_t)(b * Sdim + s0 + t) * Edim + e0) =
        pk_fp8x4(y[0], y[1], y[2], y[3]);
  }
}

// ---------------- chunked parallel scan (fp8 u, 4 e/thread) ----------------
// z is kept in u-scaled units (x CSCALE); part2 is linear so unaffected.
__global__ __launch_bounds__(256)
void scan_part1(const u8* __restrict__ u8p, const float* __restrict__ aexp,
                float* __restrict__ zloc) {
  const int c  = blockIdx.x;
  const int b  = blockIdx.y >> 1;
  const int e0 = ((blockIdx.y & 1) * 256 + threadIdx.x) * 4;
  const float4 av = *(const float4*)(aexp + e0);
  const u8* up = u8p + ((size_t)(b * Sdim + c * CL)) * Edim + e0;
  float z0 = 0.f, z1 = 0.f, z2 = 0.f, z3 = 0.f;
  #pragma unroll
  for (int t = 0; t < CL; ++t) {
    const int uv = *(const int*)(up + (size_t)t * Edim);
    z0 = fmaf(av.x, z0, dq8<0>(uv));
    z1 = fmaf(av.y, z1, dq8<1>(uv));
    z2 = fmaf(av.z, z2, dq8<2>(uv));
    z3 = fmaf(av.w, z3, dq8<3>(uv));
  }
  float4 zv = {z0, z1, z2, z3};
  *(float4*)(zloc + ((size_t)b * CH + c) * Edim + e0) = zv;
}

__global__ __launch_bounds__(256)
void scan_part2(const float* __restrict__ aexp, float* __restrict__ zloc) {
  const int idx = blockIdx.x * 256 + threadIdx.x;
  const int b = idx >> 11, e = idx & (Edim - 1);
  float a  = aexp[e];
  float aL = a * a;
  aL = aL * aL; aL = aL * aL; aL = aL * aL; aL = aL * aL;  // a^32
  float* zp = zloc + (size_t)b * CH * Edim + e;
  float pref = 0.f;
  #pragma unroll 4
  for (int c = 0; c < CH; ++c) {
    const float loc = zp[(size_t)c * Edim];
    zp[(size_t)c * Edim] = pref;
    pref = fmaf(aL, pref, loc);
  }
}

// Phase 3: re-scan, gate, write xg fp8.  y*GSCALE = Ce*(z/CSCALE)*sig*GSCALE
__global__ __launch_bounds__(256)
void scan_part3(const u8* __restrict__ u8p, const u8* __restrict__ xpg8,
                const float* __restrict__ aexp, const float* __restrict__ Ce,
                const float* __restrict__ zloc, u8* __restrict__ xg8) {
  const int c  = blockIdx.x;
  const int b  = blockIdx.y >> 1;
  const int e0 = ((blockIdx.y & 1) * 256 + threadIdx.x) * 4;
  const float4 av = *(const float4*)(aexp + e0);
  float4 Cv = *(const float4*)(Ce + e0);
  const float cs = GSCALE / CSCALE;
  Cv.x *= cs; Cv.y *= cs; Cv.z *= cs; Cv.w *= cs;
  float4 zv = *(const float4*)(zloc + ((size_t)b * CH + c) * Edim + e0);
  const u8* up = u8p  + ((size_t)(b * Sdim + c * CL)) * Edim + e0;
  const u8* gp = xpg8 + ((size_t)(b * Sdim + c * CL)) * (2 * Edim) + Edim + e0;
  u8*       op = xg8  + ((size_t)(b * Sdim + c * CL)) * Edim + e0;
  #pragma unroll 4
  for (int t = 0; t < CL; ++t) {
    const int uv = *(const int*)(up + (size_t)t * Edim);
    const int gv = *(const int*)(gp + (size_t)t * (2 * Edim));
    zv.x = fmaf(av.x, zv.x, dq8<0>(uv));
    zv.y = fmaf(av.y, zv.y, dq8<1>(uv));
    zv.z = fmaf(av.z, zv.z, dq8<2>(uv));
    zv.w = fmaf(av.w, zv.w, dq8<3>(uv));
    const float y0 = Cv.x * zv.x * sigmoidf_(dq8<0>(gv) * (1.f / XPSCALE));
    const float y1 = Cv.y * zv.y * sigmoidf_(dq8<1>(gv) * (1.f / XPSCALE));
    const float y2 = Cv.z * zv.z * sigmoidf_(dq8<2>(gv) * (1.f / XPSCALE));
    const float y3 = Cv.w * zv.w * sigmoidf_(dq8<3>(gv) * (1.f / XPSCALE));
    *(int*)(op + (size_t)t * Edim) = pk_fp8x4(y0, y1, y2, y3);
  }
}

extern "C" void kernel_launch(void* const* d_in, const int* in_sizes, int n_in,
                              void* d_out, int out_size, void* d_ws, size_t ws_size,
                              hipStream_t stream) {
  const float* x         = (const float*)d_in[0];
  const float* ln_g      = (const float*)d_in[1];
  const float* ln_b      = (const float*)d_in[2];
  const float* W_in      = (const float*)d_in[3];
  const float* b_in      = (const float*)d_in[4];
  const float* conv_w    = (const float*)d_in[5];
  const float* conv_b    = (const float*)d_in[6];
  const float* Am        = (const float*)d_in[7];
  const float* Bm        = (const float*)d_in[8];
  const float* W_c       = (const float*)d_in[9];
  const float* b_c       = (const float*)d_in[10];
  const float* W_d       = (const float*)d_in[11];
  const float* b_d       = (const float*)d_in[12];
  const float* log_delta = (const float*)d_in[13];
  const float* W_out     = (const float*)d_in[14];
  const float* b_out     = (const float*)d_in[15];
  float* out = (float*)d_out;

  const size_t MiB = 1024 * 1024;
  char* w = (char*)d_ws;
  u8*     wWin8  = (u8*)   (w + 0);             //  4 MiB
  u8*     wWc8   = (u8*)   (w + 4 * MiB);       //  4 MiB
  u8*     wWd8   = (u8*)   (w + 8 * MiB);       //  4 MiB
  u8*     wWout8 = (u8*)   (w + 12 * MiB);      //  2 MiB
  float*  aexp   = (float*)(w + 15 * MiB);
  float*  Ce     = (float*)(w + 15 * MiB + 16384);
  float*  zloc   = (float*)(w + 15 * MiB + 65536);  // 2 MiB
  u8*     xln8   = (u8*)   (w + 18 * MiB);      //  8 MiB (8192x1024)
  u8*     xpg8   = (u8*)   (w + 26 * MiB);      // 32 MiB (8192x4096)
  u8*     xc8    = (u8*)   (w + 58 * MiB);      // 16 MiB
  u8*     u8b    = (u8*)   (w + 90 * MiB);      // 16 MiB
  u8*     xg8    = (u8*)   (w + 106 * MiB);     // 16 MiB -> 122 MiB

  const int M = Bdim * Sdim;  // 8192
  const float dsIn  = 1.f / WSCALE;
  const float dsCD  = 1.f / (WSCALE * XCSCALE);
  const float dsOut = 1.f / (WSCALE * GSCALE);

  cvt_fp8_3<<<3 * 4096, 256, 0, stream>>>(W_in, W_c, W_d, wWin8, wWc8, wWd8);
  cvt_fp8<<<(Ddim * Edim) / 1024, 256, 0, stream>>>(W_out, wWout8, Ddim * Edim, WSCALE);
  prep_scalars<<<Edim / 256, 256, 0, stream>>>(log_delta, Am, Bm, aexp, Ce);

  ln_kernel<<<M, 256, 0, stream>>>(x, ln_g, ln_b, xln8);

  // xpg = fp8( (x_ln @ W_in^T + b_in) * XPSCALE )  — 128^2, 2 blocks/CU
  gemm_mx<3><<<dim3((2 * Edim) / BN, M / BM), 256, 0, stream>>>(
      xln8, wWin8, b_in, nullptr, nullptr, xpg8, nullptr, dsIn, XPSCALE, M, 2 * Edim, Ddim);

  conv_silu<<<dim3(Bdim * (Sdim / 4), Edim / 1024), 256, 0, stream>>>(xpg8, conv_w, conv_b, xc8);

  // u8b = fp8( (xc@Wc^T+bc) * sigmoid(xc@Wd^T+bd) * CSCALE ) — 256x128 dbuf T4
  gemm_cu<<<dim3(Edim / 128, M / 256), 512, 0, stream>>>(
      xc8, wWc8, wWd8, b_c, b_d, u8b, dsCD, M, Edim, Edim);

  scan_part1<<<dim3(CH, Bdim * 2), 256, 0, stream>>>(u8b, aexp, zloc);
  scan_part2<<<(Bdim * Edim) / 256, 256, 0, stream>>>(aexp, zloc);
  scan_part3<<<dim3(CH, Bdim * 2), 256, 0, stream>>>(u8b, xpg8, aexp, Ce, zloc, xg8);

  // out = xg @ W_out^T + b_out + x  — 128^2, 2 blocks/CU
  gemm_mx<1><<<dim3(Ddim / BN, M / BM), 256, 0, stream>>>(
      xg8, wWout8, b_out, nullptr, x, nullptr, out, dsOut, 1.f, M, Ddim, Edim);

  (void)in_sizes; (void)n_in; (void)out_size; (void)ws_size;
}

// Round 16
// 326.183 us; speedup vs baseline: 1.1205x; 1.0225x over previous
//
#include <hip/hip_runtime.h>
#include <hip/hip_bf16.h>

typedef __bf16 bf16_t;
typedef unsigned char u8;
typedef float  f32x4  __attribute__((ext_vector_type(4)));
typedef int    i32x4  __attribute__((ext_vector_type(4)));
typedef int    i32x8  __attribute__((ext_vector_type(8)));
typedef __attribute__((address_space(3))) unsigned as3u32;
typedef __attribute__((address_space(1))) unsigned as1u32;

#define Bdim 4
#define Sdim 2048
#define Ddim 1024
#define Edim 2048
#define CH 64
#define CL 32

#define WSCALE 32.0f   // weight fp8 pre-scale
#define XPSCALE 32.0f  // xp / gate fp8 pre-scale
#define XCSCALE 16.0f  // conv output fp8 pre-scale
#define CSCALE 16.0f   // c and u fp8 pre-scale
#define GSCALE 256.0f  // xg fp8 pre-scale

__device__ __forceinline__ void gload_lds16(const void* g, void* l) {
  __builtin_amdgcn_global_load_lds((const as1u32*)g, (as3u32*)l, 16, 0, 0);
}
__device__ __forceinline__ float sigmoidf_(float x) {
  return 1.f / (1.f + __expf(-x));
}
__device__ __forceinline__ int pk_fp8x4(float a, float b, float c, float d) {
  int p = __builtin_amdgcn_cvt_pk_fp8_f32(a, b, 0, 0);
  p = __builtin_amdgcn_cvt_pk_fp8_f32(c, d, p, 1);
  return p;
}
template<int K>
__device__ __forceinline__ float dq8(int v) {
  return __builtin_amdgcn_cvt_f32_fp8(v, K);   // K must be a front-end constant
}
__device__ __forceinline__ u8 q8(float v) {
  return (u8)(__builtin_amdgcn_cvt_pk_fp8_f32(v, v, 0, 0) & 0xff);
}

// ============ fused prep: weight cvt x4 + scan scalars + layernorm ============
// R15 audit: device work ~215 us vs 333 measured -> ~110 us of inter-launch
// gaps across 11 serialized launches. These four kernels are mutually
// independent; fusing them (block-range branching, block-uniform) cuts 3
// launches. Work per block identical to the unfused versions.
// blocks [0,12288): W_in/W_c/W_d fp32->fp8   [12288,14336): W_out
// [14336,14344): prep_scalars               [14344,22536): layernorm
__global__ __launch_bounds__(256)
void prep_all(const float* __restrict__ W_in, const float* __restrict__ W_c,
              const float* __restrict__ W_d, u8* __restrict__ wWin8,
              u8* __restrict__ wWc8, u8* __restrict__ wWd8,
              const float* __restrict__ W_out, u8* __restrict__ wWout8,
              const float* __restrict__ ld, const float* __restrict__ Am,
              const float* __restrict__ Bm, float* __restrict__ aexp,
              float* __restrict__ Ce, const float* __restrict__ x,
              const float* __restrict__ g, const float* __restrict__ b,
              u8* __restrict__ xln8) {
  const int blk = blockIdx.x;
  const int tid = threadIdx.x;
  if (blk < 12288) {
    const int seg = blk >> 12;
    const int i   = ((blk & 4095) * 256 + tid) * 4;
    const float* s = (seg == 0) ? W_in : (seg == 1) ? W_c : W_d;
    u8*          d = (seg == 0) ? wWin8 : (seg == 1) ? wWc8 : wWd8;
    *(int*)(d + i) = pk_fp8x4(s[i] * WSCALE, s[i + 1] * WSCALE,
                              s[i + 2] * WSCALE, s[i + 3] * WSCALE);
  } else if (blk < 14336) {
    const int i = ((blk - 12288) * 256 + tid) * 4;
    *(int*)(wWout8 + i) = pk_fp8x4(W_out[i] * WSCALE, W_out[i + 1] * WSCALE,
                                   W_out[i + 2] * WSCALE, W_out[i + 3] * WSCALE);
  } else if (blk < 14344) {
    const int e = (blk - 14336) * 256 + tid;
    if (e < Edim) {
      float d = ld[e];
      float sp = (d > 20.f) ? d : log1pf(expf(d));
      aexp[e] = expf(-sp);
      float s = 0.f;
      #pragma unroll
      for (int n = 0; n < 16; ++n) s += Am[e * 16 + n] * Bm[e * 16 + n];
      Ce[e] = s;
    }
  } else {
    const int row = blk - 14344;
    const float4 v = ((const float4*)(x + (size_t)row * Ddim))[tid];
    float s  = v.x + v.y + v.z + v.w;
    float ss = v.x * v.x + v.y * v.y + v.z * v.z + v.w * v.w;
    #pragma unroll
    for (int o = 32; o > 0; o >>= 1) { s += __shfl_down(s, o); ss += __shfl_down(ss, o); }
    __shared__ float sh[8];
    const int wv = tid >> 6, lane = tid & 63;
    if (lane == 0) { sh[wv] = s; sh[4 + wv] = ss; }
    __syncthreads();
    s  = sh[0] + sh[1] + sh[2] + sh[3];
    ss = sh[4] + sh[5] + sh[6] + sh[7];
    const float mean = s * (1.f / Ddim);
    const float var  = ss * (1.f / Ddim) - mean * mean;
    const float rstd = rsqrtf(var + 1e-5f);
    const float4 gv = ((const float4*)g)[tid];
    const float4 bv = ((const float4*)b)[tid];
    *(int*)(xln8 + (size_t)row * Ddim + tid * 4) =
        pk_fp8x4((v.x - mean) * rstd * gv.x + bv.x,
                 (v.y - mean) * rstd * gv.y + bv.y,
                 (v.z - mean) * rstd * gv.z + bv.z,
                 (v.w - mean) * rstd * gv.w + bv.w);
  }
}

// ============ MX fp8 GEMM_BT: 128x128 tile, BK=256, mfma_scale 16x16x128 =========
// acc = A8 @ B8^T; v = acc*descale + bias.
// MODE 1: Cf[idx] = v + R[idx]     MODE 3: C8[idx] = fp8( v * oscale )
// Register-safe: acc 64 AGPR + ~112 arch -> 2 blocks/CU (cross-block overlap —
// R14 lesson: big tiles regress here because K is shallow, 4-8 iters).
#define BM 128
#define BN 128

template<int MODE>
__global__ __launch_bounds__(256)
void gemm_mx(const u8* __restrict__ A, const u8* __restrict__ Bw,
             const float* __restrict__ bias, const u8* __restrict__ X,
             const float* __restrict__ R, u8* __restrict__ C8,
             float* __restrict__ Cf, float descale, float oscale,
             int M, int N, int K) {
  __shared__ __align__(16) u8 As[BM * 256];   // 32 KB
  __shared__ __align__(16) u8 Bs[BN * 256];   // 32 KB

  const int tid  = threadIdx.x;
  const int lane = tid & 63;
  const int wv   = tid >> 6;
  const int m0   = blockIdx.y * BM;
  const int n0   = blockIdx.x * BN;

  const int wr = (wv >> 1) * 64;
  const int wc = (wv & 1) * 64;
  const int tq = lane >> 4;
  const int tr = lane & 15;

  f32x4 acc[4][4] = {};

  // chunk = 256 thr x 16B = 4 KB = 16 rows of 256 B. 8 chunks per matrix.
  const int    srow  = tid >> 4;                 // 0..15 within chunk
  const int    sc16  = tid & 15;                 // 16B slot 0..15
  const int    shalf = sc16 >> 3;                // which 128B half
  const int    s3    = (sc16 & 7) ^ (srow & 7);  // swizzled slot in half
  const size_t sBase = (size_t)srow * K + shalf * 128 + s3 * 16;
  const size_t rStep = (size_t)16 * K;           // rows per chunk
  const u8* Ap = A  + (size_t)m0 * K + sBase;
  const u8* Bp = Bw + (size_t)n0 * K + sBase;
  const int ldsW = wv * 1024;

  const int s7 = tr & 7;
  const int p0 = (((tq << 1)) ^ s7) * 16;
  const int p1 = (((tq << 1) | 1) ^ s7) * 16;

  for (int k0 = 0; k0 < K; k0 += 256) {
    __syncthreads();
    #pragma unroll
    for (int g = 0; g < 8; ++g)
      gload_lds16(Ap + g * rStep + k0, (u8*)As + g * 4096 + ldsW);
    #pragma unroll
    for (int g = 0; g < 8; ++g)
      gload_lds16(Bp + g * rStep + k0, (u8*)Bs + g * 4096 + ldsW);
    __syncthreads();

    #pragma unroll
    for (int kk = 0; kk < 256; kk += 128) {
      i32x8 aF[4], bF[4];
      #pragma unroll
      for (int i = 0; i < 4; ++i) {
        const int rb = (wr + i * 16 + tr) * 256 + kk;
        const i32x4 lo = *(const i32x4*)&As[rb + p0];
        const i32x4 hi = *(const i32x4*)&As[rb + p1];
        aF[i] = __builtin_shufflevector(lo, hi, 0, 1, 2, 3, 4, 5, 6, 7);
      }
      #pragma unroll
      for (int j = 0; j < 4; ++j) {
        const int rb = (wc + j * 16 + tr) * 256 + kk;
        const i32x4 lo = *(const i32x4*)&Bs[rb + p0];
        const i32x4 hi = *(const i32x4*)&Bs[rb + p1];
        bF[j] = __builtin_shufflevector(lo, hi, 0, 1, 2, 3, 4, 5, 6, 7);
      }
      #pragma unroll
      for (int i = 0; i < 4; ++i)
        #pragma unroll
        for (int j = 0; j < 4; ++j)
          acc[i][j] = __builtin_amdgcn_mfma_scale_f32_16x16x128_f8f6f4(
              aF[i], bF[j], acc[i][j], 0, 0, 0, 0x7F, 0, 0x7F);
    }
  }

  #pragma unroll
  for (int i = 0; i < 4; ++i) {
    #pragma unroll
    for (int j = 0; j < 4; ++j) {
      const int col = n0 + wc + j * 16 + tr;
      const float bv = bias[col];
      #pragma unroll
      for (int r = 0; r < 4; ++r) {
        const int rowg = m0 + wr + i * 16 + tq * 4 + r;
        const size_t idx = (size_t)rowg * N + col;
        const float v = acc[i][j][r] * descale + bv;
        if (MODE == 1) {
          Cf[idx] = v + R[idx];
        } else {
          C8[idx] = q8(v * oscale);
        }
      }
    }
  }
}

// ============ fused c/u GEMM: 256x128 block, 512 thr, BK=128 DOUBLE-BUFFERED ====
// u = (A@Wc^T+bc)*sigmoid(A@Wd^T+bd). 1 block/CU -> no implicit cross-block
// overlap, so explicit dbuf + counted vmcnt pays here (R15: 66 -> 61.5 us).
// Static dual buffers (4 x 32 KB = 128 KB); per tile {ds_read; setprio MFMA;
// barrier; stage t+2 into just-freed buffer; vmcnt(8); barrier}.
// Wave tile 64x64 -> accC+accD = 64 AGPR, ~124 arch VGPR.
#define CUT2(AS, BS, t_)                                                       \
  {                                                                            \
    i32x8 aF[4], bC[2], bD[2];                                                 \
    _Pragma("unroll") for (int j_ = 0; j_ < 2; ++j_) {                         \
      const int rbc = (wc + j_ * 16 + tr) * 128;                               \
      const i32x4 loc = *(const i32x4*)&(BS)[rbc + p0];                        \
      const i32x4 hic = *(const i32x4*)&(BS)[rbc + p1];                        \
      bC[j_] = __builtin_shufflevector(loc, hic, 0, 1, 2, 3, 4, 5, 6, 7);      \
      const int rbd = (128 + wc + j_ * 16 + tr) * 128;                         \
      const i32x4 lod = *(const i32x4*)&(BS)[rbd + p0];                        \
      const i32x4 hid = *(const i32x4*)&(BS)[rbd + p1];                        \
      bD[j_] = __builtin_shufflevector(lod, hid, 0, 1, 2, 3, 4, 5, 6, 7);      \
    }                                                                          \
    _Pragma("unroll") for (int i_ = 0; i_ < 4; ++i_) {                         \
      const int rb = (wr + i_ * 16 + tr) * 128;                                \
      const i32x4 lo = *(const i32x4*)&(AS)[rb + p0];                          \
      const i32x4 hi = *(const i32x4*)&(AS)[rb + p1];                          \
      aF[i_] = __builtin_shufflevector(lo, hi, 0, 1, 2, 3, 4, 5, 6, 7);        \
    }                                                                          \
    __builtin_amdgcn_s_setprio(1);                                             \
    _Pragma("unroll") for (int i_ = 0; i_ < 4; ++i_)                           \
      _Pragma("unroll") for (int j_ = 0; j_ < 2; ++j_) {                       \
        accC[i_][j_] = __builtin_amdgcn_mfma_scale_f32_16x16x128_f8f6f4(       \
            aF[i_], bC[j_], accC[i_][j_], 0, 0, 0, 0x7F, 0, 0x7F);             \
        accD[i_][j_] = __builtin_amdgcn_mfma_scale_f32_16x16x128_f8f6f4(       \
            aF[i_], bD[j_], accD[i_][j_], 0, 0, 0, 0x7F, 0, 0x7F);             \
      }                                                                        \
    __builtin_amdgcn_s_setprio(0);                                             \
    __builtin_amdgcn_s_barrier();                                              \
    if ((t_) + 2 < NK) {                                                       \
      const size_t ko_ = (size_t)((t_) + 2) * 128;                             \
      _Pragma("unroll") for (int g_ = 0; g_ < 4; ++g_)                         \
        gload_lds16(Ap + g_ * rStep + ko_, (u8*)(AS) + g_ * 8192 + ldsW);      \
      _Pragma("unroll") for (int g_ = 0; g_ < 2; ++g_)                         \
        gload_lds16(Cp + g_ * rStep + ko_, (u8*)(BS) + g_ * 8192 + ldsW);      \
      _Pragma("unroll") for (int g_ = 0; g_ < 2; ++g_)                         \
        gload_lds16(Dp + g_ * rStep + ko_, (u8*)(BS) + 16384 + g_ * 8192 + ldsW); \
      asm volatile("s_waitcnt vmcnt(8)" ::: "memory");                         \
    } else {                                                                   \
      asm volatile("s_waitcnt vmcnt(0)" ::: "memory");                         \
    }                                                                          \
    __builtin_amdgcn_s_barrier();                                              \
  }

__global__ __launch_bounds__(512)
void gemm_cu(const u8* __restrict__ A, const u8* __restrict__ Wc8,
             const u8* __restrict__ Wd8, const float* __restrict__ bias_c,
             const float* __restrict__ bias_d, u8* __restrict__ U8,
             float descale, int M, int N, int K) {
  __shared__ __align__(16) u8 As0[256 * 128];  // 32 KB
  __shared__ __align__(16) u8 Bs0[256 * 128];  // 32 KB: 128 Wc rows + 128 Wd rows
  __shared__ __align__(16) u8 As1[256 * 128];
  __shared__ __align__(16) u8 Bs1[256 * 128];

  const int tid  = threadIdx.x;
  const int lane = tid & 63;
  const int wv   = tid >> 6;           // 0..7
  const int m0   = blockIdx.y * 256;
  const int n0   = blockIdx.x * 128;

  const int wr = (wv >> 1) * 64;       // rows 0/64/128/192
  const int wc = (wv & 1) * 64;        // cols 0/64
  const int tq = lane >> 4;
  const int tr = lane & 15;

  f32x4 accC[4][2] = {};
  f32x4 accD[4][2] = {};

  // chunk = 512 thr x 16B = 8 KB = 64 rows of 128 B. A: 4 chunks; Wc 2; Wd 2.
  const int    srow = tid >> 3;                  // 0..63 within chunk
  const int    scol = (tid & 7) ^ (srow & 7);
  const size_t sBase = (size_t)srow * K + (size_t)scol * 16;
  const size_t rStep = (size_t)64 * K;           // rows per chunk
  const u8* Ap = A   + (size_t)m0 * K + sBase;
  const u8* Cp = Wc8 + (size_t)n0 * K + sBase;
  const u8* Dp = Wd8 + (size_t)n0 * K + sBase;
  const int ldsW = wv * 1024;                    // 8 waves x 1 KB = 8 KB/chunk

  const int s7 = tr & 7;
  const int p0 = (((tq << 1)) ^ s7) * 16;
  const int p1 = (((tq << 1) | 1) ^ s7) * 16;

  const int NK = K >> 7;   // 16

  // prologue: tile 0 -> buf0, tile 1 -> buf1; wait tile0 (tile1 in flight)
  #pragma unroll
  for (int g = 0; g < 4; ++g)
    gload_lds16(Ap + g * rStep, (u8*)As0 + g * 8192 + ldsW);
  #pragma unroll
  for (int g = 0; g < 2; ++g)
    gload_lds16(Cp + g * rStep, (u8*)Bs0 + g * 8192 + ldsW);
  #pragma unroll
  for (int g = 0; g < 2; ++g)
    gload_lds16(Dp + g * rStep, (u8*)Bs0 + 16384 + g * 8192 + ldsW);
  #pragma unroll
  for (int g = 0; g < 4; ++g)
    gload_lds16(Ap + g * rStep + 128, (u8*)As1 + g * 8192 + ldsW);
  #pragma unroll
  for (int g = 0; g < 2; ++g)
    gload_lds16(Cp + g * rStep + 128, (u8*)Bs1 + g * 8192 + ldsW);
  #pragma unroll
  for (int g = 0; g < 2; ++g)
    gload_lds16(Dp + g * rStep + 128, (u8*)Bs1 + 16384 + g * 8192 + ldsW);
  asm volatile("s_waitcnt vmcnt(8)" ::: "memory");
  __builtin_amdgcn_s_barrier();

  for (int tp = 0; tp < (NK >> 1); ++tp) {
    const int t0 = tp * 2;
    CUT2(As0, Bs0, t0);
    CUT2(As1, Bs1, t0 + 1);
  }

  #pragma unroll
  for (int i = 0; i < 4; ++i) {
    #pragma unroll
    for (int j = 0; j < 2; ++j) {
      const int col = n0 + wc + j * 16 + tr;
      const float bc = bias_c[col];
      const float bd = bias_d[col];
      #pragma unroll
      for (int r = 0; r < 4; ++r) {
        const int rowg = m0 + wr + i * 16 + tq * 4 + r;
        const size_t idx = (size_t)rowg * N + col;
        const float vc = accC[i][j][r] * descale + bc;
        const float vd = accD[i][j][r] * descale + bd;
        U8[idx] = q8(vc * CSCALE * sigmoidf_(vd));   // = u * CSCALE
      }
    }
  }
}

// ---------------- causal depthwise conv (K=4) + silu, fp8 in/out, 4 e/thread ----
__global__ __launch_bounds__(256)
void conv_silu(const u8* __restrict__ xpg8, const float* __restrict__ cw,
               const float* __restrict__ cb, u8* __restrict__ xc8) {
  const int e0 = (blockIdx.y * 256 + threadIdx.x) * 4;   // gridDim.y = Edim/1024
  const int b  = blockIdx.x >> 9;
  const int s0 = (blockIdx.x & 511) * 4;
  float w[4][4], bias[4];
  #pragma unroll
  for (int k = 0; k < 4; ++k) {
    const float4 wv = *(const float4*)(cw + (e0 + k) * 4);
    w[k][0] = wv.x; w[k][1] = wv.y; w[k][2] = wv.z; w[k][3] = wv.w;
    bias[k] = cb[e0 + k];
  }
  float f[7][4];
  #pragma unroll
  for (int j = 0; j < 7; ++j) {
    const int s = s0 - 3 + j;
    const int xv = (s >= 0) ? *(const int*)(xpg8 + (size_t)(b * Sdim + s) * (2 * Edim) + e0) : 0;
    f[j][0] = dq8<0>(xv); f[j][1] = dq8<1>(xv);
    f[j][2] = dq8<2>(xv); f[j][3] = dq8<3>(xv);
  }
  #pragma unroll
  for (int t = 0; t < 4; ++t) {
    float y[4];
    #pragma unroll
    for (int k = 0; k < 4; ++k) {
      float a = fmaf(w[k][0], f[t][k],
               fmaf(w[k][1], f[t + 1][k],
               fmaf(w[k][2], f[t + 2][k],
                    w[k][3] * f[t + 3][k])));
      a = a * (1.f / XPSCALE) + bias[k];
      y[k] = a * sigmoidf_(a) * XCSCALE;
    }
    *(int*)(xc8 + (size_t)(b * Sdim + s0 + t) * Edim + e0) =
        pk_fp8x4(y[0], y[1], y[2], y[3]);
  }
}

// ---------------- chunked parallel scan (fp8 u, 4 e/thread) ----------------
// z is kept in u-scaled units (x CSCALE); part2 is linear so unaffected.
__global__ __launch_bounds__(256)
void scan_part1(const u8* __restrict__ u8p, const float* __restrict__ aexp,
                float* __restrict__ zloc) {
  const int c  = blockIdx.x;
  const int b  = blockIdx.y >> 1;
  const int e0 = ((blockIdx.y & 1) * 256 + threadIdx.x) * 4;
  const float4 av = *(const float4*)(aexp + e0);
  const u8* up = u8p + ((size_t)(b * Sdim + c * CL)) * Edim + e0;
  float z0 = 0.f, z1 = 0.f, z2 = 0.f, z3 = 0.f;
  #pragma unroll
  for (int t = 0; t < CL; ++t) {
    const int uv = *(const int*)(up + (size_t)t * Edim);
    z0 = fmaf(av.x, z0, dq8<0>(uv));
    z1 = fmaf(av.y, z1, dq8<1>(uv));
    z2 = fmaf(av.z, z2, dq8<2>(uv));
    z3 = fmaf(av.w, z3, dq8<3>(uv));
  }
  float4 zv = {z0, z1, z2, z3};
  *(float4*)(zloc + ((size_t)b * CH + c) * Edim + e0) = zv;
}

__global__ __launch_bounds__(256)
void scan_part2(const float* __restrict__ aexp, float* __restrict__ zloc) {
  const int idx = blockIdx.x * 256 + threadIdx.x;
  const int b = idx >> 11, e = idx & (Edim - 1);
  float a  = aexp[e];
  float aL = a * a;
  aL = aL * aL; aL = aL * aL; aL = aL * aL; aL = aL * aL;  // a^32
  float* zp = zloc + (size_t)b * CH * Edim + e;
  float pref = 0.f;
  #pragma unroll 4
  for (int c = 0; c < CH; ++c) {
    const float loc = zp[(size_t)c * Edim];
    zp[(size_t)c * Edim] = pref;
    pref = fmaf(aL, pref, loc);
  }
}

// Phase 3: re-scan, gate, write xg fp8.  y*GSCALE = Ce*(z/CSCALE)*sig*GSCALE
__global__ __launch_bounds__(256)
void scan_part3(const u8* __restrict__ u8p, const u8* __restrict__ xpg8,
                const float* __restrict__ aexp, const float* __restrict__ Ce,
                const float* __restrict__ zloc, u8* __restrict__ xg8) {
  const int c  = blockIdx.x;
  const int b  = blockIdx.y >> 1;
  const int e0 = ((blockIdx.y & 1) * 256 + threadIdx.x) * 4;
  const float4 av = *(const float4*)(aexp + e0);
  float4 Cv = *(const float4*)(Ce + e0);
  const float cs = GSCALE / CSCALE;
  Cv.x *= cs; Cv.y *= cs; Cv.z *= cs; Cv.w *= cs;
  float4 zv = *(const float4*)(zloc + ((size_t)b * CH + c) * Edim + e0);
  const u8* up = u8p  + ((size_t)(b * Sdim + c * CL)) * Edim + e0;
  const u8* gp = xpg8 + ((size_t)(b * Sdim + c * CL)) * (2 * Edim) + Edim + e0;
  u8*       op = xg8  + ((size_t)(b * Sdim + c * CL)) * Edim + e0;
  #pragma unroll 4
  for (int t = 0; t < CL; ++t) {
    const int uv = *(const int*)(up + (size_t)t * Edim);
    const int gv = *(const int*)(gp + (size_t)t * (2 * Edim));
    zv.x = fmaf(av.x, zv.x, dq8<0>(uv));
    zv.y = fmaf(av.y, zv.y, dq8<1>(uv));
    zv.z = fmaf(av.z, zv.z, dq8<2>(uv));
    zv.w = fmaf(av.w, zv.w, dq8<3>(uv));
    const float y0 = Cv.x * zv.x * sigmoidf_(dq8<0>(gv) * (1.f / XPSCALE));
    const float y1 = Cv.y * zv.y * sigmoidf_(dq8<1>(gv) * (1.f / XPSCALE));
    const float y2 = Cv.z * zv.z * sigmoidf_(dq8<2>(gv) * (1.f / XPSCALE));
    const float y3 = Cv.w * zv.w * sigmoidf_(dq8<3>(gv) * (1.f / XPSCALE));
    *(int*)(op + (size_t)t * Edim) = pk_fp8x4(y0, y1, y2, y3);
  }
}

extern "C" void kernel_launch(void* const* d_in, const int* in_sizes, int n_in,
                              void* d_out, int out_size, void* d_ws, size_t ws_size,
                              hipStream_t stream) {
  const float* x         = (const float*)d_in[0];
  const float* ln_g      = (const float*)d_in[1];
  const float* ln_b      = (const float*)d_in[2];
  const float* W_in      = (const float*)d_in[3];
  const float* b_in      = (const float*)d_in[4];
  const float* conv_w    = (const float*)d_in[5];
  const float* conv_b    = (const float*)d_in[6];
  const float* Am        = (const float*)d_in[7];
  const float* Bm        = (const float*)d_in[8];
  const float* W_c       = (const float*)d_in[9];
  const float* b_c       = (const float*)d_in[10];
  const float* W_d       = (const float*)d_in[11];
  const float* b_d       = (const float*)d_in[12];
  const float* log_delta = (const float*)d_in[13];
  const float* W_out     = (const float*)d_in[14];
  const float* b_out     = (const float*)d_in[15];
  float* out = (float*)d_out;

  const size_t MiB = 1024 * 1024;
  char* w = (char*)d_ws;
  u8*     wWin8  = (u8*)   (w + 0);             //  4 MiB
  u8*     wWc8   = (u8*)   (w + 4 * MiB);       //  4 MiB
  u8*     wWd8   = (u8*)   (w + 8 * MiB);       //  4 MiB
  u8*     wWout8 = (u8*)   (w + 12 * MiB);      //  2 MiB
  float*  aexp   = (float*)(w + 15 * MiB);
  float*  Ce     = (float*)(w + 15 * MiB + 16384);
  float*  zloc   = (float*)(w + 15 * MiB + 65536);  // 2 MiB
  u8*     xln8   = (u8*)   (w + 18 * MiB);      //  8 MiB (8192x1024)
  u8*     xpg8   = (u8*)   (w + 26 * MiB);      // 32 MiB (8192x4096)
  u8*     xc8    = (u8*)   (w + 58 * MiB);      // 16 MiB
  u8*     u8b    = (u8*)   (w + 90 * MiB);      // 16 MiB
  u8*     xg8    = (u8*)   (w + 106 * MiB);     // 16 MiB -> 122 MiB

  const int M = Bdim * Sdim;  // 8192
  const float dsIn  = 1.f / WSCALE;
  const float dsCD  = 1.f / (WSCALE * XCSCALE);
  const float dsOut = 1.f / (WSCALE * GSCALE);

  // fused prep: 12288 cvt3 + 2048 cvtWout + 8 scalars + 8192 ln = 22536 blocks
  prep_all<<<22536, 256, 0, stream>>>(W_in, W_c, W_d, wWin8, wWc8, wWd8,
                                      W_out, wWout8, log_delta, Am, Bm,
                                      aexp, Ce, x, ln_g, ln_b, xln8);

  // xpg = fp8( (x_ln @ W_in^T + b_in) * XPSCALE )  — 128^2, 2 blocks/CU
  gemm_mx<3><<<dim3((2 * Edim) / BN, M / BM), 256, 0, stream>>>(
      xln8, wWin8, b_in, nullptr, nullptr, xpg8, nullptr, dsIn, XPSCALE, M, 2 * Edim, Ddim);

  conv_silu<<<dim3(Bdim * (Sdim / 4), Edim / 1024), 256, 0, stream>>>(xpg8, conv_w, conv_b, xc8);

  // u8b = fp8( (xc@Wc^T+bc) * sigmoid(xc@Wd^T+bd) * CSCALE ) — 256x128 dbuf T4
  gemm_cu<<<dim3(Edim / 128, M / 256), 512, 0, stream>>>(
      xc8, wWc8, wWd8, b_c, b_d, u8b, dsCD, M, Edim, Edim);

  scan_part1<<<dim3(CH, Bdim * 2), 256, 0, stream>>>(u8b, aexp, zloc);
  scan_part2<<<(Bdim * Edim) / 256, 256, 0, stream>>>(aexp, zloc);
  scan_part3<<<dim3(CH, Bdim * 2), 256, 0, stream>>>(u8b, xpg8, aexp, Ce, zloc, xg8);

  // out = xg @ W_out^T + b_out + x  — 128^2, 2 blocks/CU
  gemm_mx<1><<<dim3(Ddim / BN, M / BM), 256, 0, stream>>>(
      xg8, wWout8, b_out, nullptr, x, nullptr, out, dsOut, 1.f, M, Ddim, Edim);

  (void)in_sizes; (void)n_in; (void)out_size; (void)ws_size;
}